// Round 8
// baseline (1629.262 us; speedup 1.0000x reference)
//
#include <hip/hip_runtime.h>
#include <math.h>

typedef short bf16x8 __attribute__((ext_vector_type(8)));
typedef float f32x4 __attribute__((ext_vector_type(4)));

__device__ __forceinline__ float sigf(float x) {
    return __builtin_amdgcn_rcpf(1.f + __expf(-x));
}
__device__ __forceinline__ float tanhf_fast(float x) {
    const float e = __expf(2.f * x);           // inf for big x -> 1; 0 -> -1
    return 1.f - 2.f * __builtin_amdgcn_rcpf(e + 1.f);
}

__device__ __forceinline__ unsigned short f2bf(float f) {
    union { float f; unsigned u; } v; v.f = f;
    unsigned r = (v.u + 0x7FFFu + ((v.u >> 16) & 1u)) >> 16;
    return (unsigned short)r;
}
__device__ __forceinline__ float bf2f(unsigned short u) {
    union { unsigned u; float f; } v; v.u = ((unsigned)u) << 16; return v.f;
}

// async global->LDS, 16B per lane; LDS dest = wave-uniform base + lane*16B.
__device__ __forceinline__ void gload16(const unsigned short* g, unsigned short* l) {
    __builtin_amdgcn_global_load_lds(
        (const __attribute__((address_space(1))) void*)g,
        (__attribute__((address_space(3))) void*)l, 16, 0, 0);
}

// Chunk = 16 rows x 32 ushorts (1 KiB). Lane i -> (row=i>>2, slot=i&3).
// Both-sides bank swizzle: source col = (slot ^ ((row>>1)&3))*8; LDS linear;
// reads use the same XOR.
__device__ __forceinline__ int swz(int slot, int row) {
    return (slot ^ ((row >> 1) & 3)) * 8;
}

// Software grid barrier. Arrival: one atomicAdd per block (RMW, 512 total).
// Spin: relaxed agent-scope atomic LOAD (coherent global_load, broadcastable,
// does NOT serialize like an RMW spin) + s_sleep backoff. Release via
// release-store. All blocks must be co-resident.
__device__ __forceinline__ void grid_sync(unsigned* cnt, unsigned* gen,
                                          unsigned nb, unsigned my)
{
    __syncthreads();
    if (threadIdx.x == 0) {
        __threadfence();
        if (atomicAdd(cnt, 1u) == nb - 1u) {
            atomicExch(cnt, 0u);   // reset before release; none can re-enter yet
            __hip_atomic_store(gen, my + 1u, __ATOMIC_RELEASE,
                               __HIP_MEMORY_SCOPE_AGENT);
        } else {
            while (__hip_atomic_load(gen, __ATOMIC_ACQUIRE,
                                     __HIP_MEMORY_SCOPE_AGENT) <= my)
                __builtin_amdgcn_s_sleep(8);
        }
        __threadfence();
    }
    __syncthreads();
}

// ---------------------------------------------------------------------------
// prep kernels
// ---------------------------------------------------------------------------
__global__ void cvt_f32_bf16(const float* __restrict__ src,
                             unsigned short* __restrict__ dst, int n)
{
    const int i = (blockIdx.x * blockDim.x + threadIdx.x) * 4;
    if (i >= n) return;
    const float4 v = *reinterpret_cast<const float4*>(src + i);
    ushort4 o;
    o.x = f2bf(v.x); o.y = f2bf(v.y); o.z = f2bf(v.z); o.w = f2bf(v.w);
    *reinterpret_cast<ushort4*>(dst + i) = o;
}

__global__ void transpose_cvt(const float* __restrict__ src,
                              unsigned short* __restrict__ dst,
                              int rows, int cols)
{
    __shared__ float tile[32][33];
    const int bc = blockIdx.x * 32, br = blockIdx.y * 32;
    const int tx = threadIdx.x, ty = threadIdx.y;  // block (32,8)
    #pragma unroll
    for (int i = 0; i < 32; i += 8)
        tile[ty + i][tx] = src[(size_t)(br + ty + i) * cols + bc + tx];
    __syncthreads();
    #pragma unroll
    for (int i = 0; i < 32; i += 8)
        dst[(size_t)(bc + ty + i) * rows + br + tx] = f2bf(tile[tx][ty + i]);
}

// ---------------------------------------------------------------------------
// Fused GRU: ALL L steps in one kernel. Grid 512 blocks (2/CU co-resident:
// 60KiB LDS caps at exactly 2/CU), load-spin grid barrier between steps.
// 3-buffer 3-deep counted-vmcnt pipeline per step; next step's pass-1 tiles
// (h-independent) are prefetched BEFORE the barrier to hide under the wait.
// ---------------------------------------------------------------------------
__global__ __launch_bounds__(256, 2)
void gru_fused(const unsigned short* __restrict__ xb,
               const unsigned short* __restrict__ WihT,
               const unsigned short* __restrict__ WhhT,
               const float* __restrict__ b_ih, const float* __restrict__ b_hh,
               unsigned short* __restrict__ hb0,
               unsigned short* __restrict__ hb1,
               int L, unsigned* __restrict__ bar)
{
    constexpr int I = 256, H = 512, LI = 2048;
    const int bx = blockIdx.x;
    const int m0 = (bx >> 3) * 128, j0 = (bx & 7) * 64;
    const int tid = (int)threadIdx.x, lane = tid & 63, wid = tid >> 6;
    const int wm = wid >> 1, wn = wid & 1;
    const int fr = lane & 15, kg = lane >> 4;
    const int lrow = lane >> 2;
    const int scol = swz(lane & 3, lrow);

    __shared__ unsigned short smem[3 * 10240];

    constexpr int nkt1 = I / 32;          // 8
    constexpr int nkt = (I + H) / 32;     // 24

    const unsigned short* hbi = hb0;

    auto stage = [&](int buf, int kt, int tt) {
        const bool s1 = (kt < nkt1);
        const int k0 = s1 ? kt * 32 : (kt - nkt1) * 32;
        unsigned short* base = &smem[buf * 10240];
        #pragma unroll
        for (int q = 0; q < 5; ++q) {
            const int c = wid * 5 + q;     // 20 chunks of 1 KiB
            if (c < 8) {
                const int row = c * 16 + lrow;
                const unsigned short* g = s1
                    ? xb + (size_t)(m0 + row) * LI + tt * I + k0 + scol
                    : hbi + (size_t)(m0 + row) * H + k0 + scol;
                gload16(g, base + c * 512);
            } else {
                const int bc = c - 8, gi = bc >> 2;
                const int row = (bc & 3) * 16 + lrow;
                const unsigned short* g = s1
                    ? WihT + (size_t)(gi * H + j0 + row) * I + k0 + scol
                    : WhhT + (size_t)(gi * H + j0 + row) * H + k0 + scol;
                gload16(g, base + c * 512);
            }
        }
    };

    stage(0, 0, 0); stage(1, 1, 0); stage(2, 2, 0);

    for (int t = 0; t < L; ++t) {
        hbi = (t & 1) ? hb1 : hb0;
        unsigned short* hbo = (t & 1) ? hb0 : hb1;

        f32x4 ar[4][2], az[4][2], an[4][2], ah[4][2];
        #pragma unroll
        for (int i = 0; i < 4; ++i)
            #pragma unroll
            for (int j = 0; j < 2; ++j) {
                ar[i][j] = (f32x4){0.f, 0.f, 0.f, 0.f};
                az[i][j] = (f32x4){0.f, 0.f, 0.f, 0.f};
                an[i][j] = (f32x4){0.f, 0.f, 0.f, 0.f};
                ah[i][j] = (f32x4){0.f, 0.f, 0.f, 0.f};
            }

        int cur = 0;
        for (int kt = 0; kt < nkt; ++kt) {
            if (kt + 2 < nkt)      asm volatile("s_waitcnt vmcnt(10)" ::: "memory");
            else if (kt + 1 < nkt) asm volatile("s_waitcnt vmcnt(5)" ::: "memory");
            else                   asm volatile("s_waitcnt vmcnt(0)" ::: "memory");
            __builtin_amdgcn_s_barrier();

            const unsigned short* sb = &smem[cur * 10240];
            bf16x8 af[4], bfr[2], bfz[2], bfn[2];
            #pragma unroll
            for (int mi = 0; mi < 4; ++mi) {
                const int row = wm * 64 + mi * 16 + fr;
                af[mi] = *reinterpret_cast<const bf16x8*>(&sb[row * 32 + swz(kg, row)]);
            }
            #pragma unroll
            for (int ni = 0; ni < 2; ++ni) {
                const int row = wn * 32 + ni * 16 + fr;
                const int sw = swz(kg, row);
                bfr[ni] = *reinterpret_cast<const bf16x8*>(&sb[4096 + (row) * 32 + sw]);
                bfz[ni] = *reinterpret_cast<const bf16x8*>(&sb[4096 + (64 + row) * 32 + sw]);
                bfn[ni] = *reinterpret_cast<const bf16x8*>(&sb[4096 + (128 + row) * 32 + sw]);
            }
            const bool p1 = (kt < nkt1);
            #pragma unroll
            for (int mi = 0; mi < 4; ++mi)
                #pragma unroll
                for (int ni = 0; ni < 2; ++ni) {
                    ar[mi][ni] = __builtin_amdgcn_mfma_f32_16x16x32_bf16(af[mi], bfr[ni], ar[mi][ni], 0, 0, 0);
                    az[mi][ni] = __builtin_amdgcn_mfma_f32_16x16x32_bf16(af[mi], bfz[ni], az[mi][ni], 0, 0, 0);
                    if (p1)
                        an[mi][ni] = __builtin_amdgcn_mfma_f32_16x16x32_bf16(af[mi], bfn[ni], an[mi][ni], 0, 0, 0);
                    else
                        ah[mi][ni] = __builtin_amdgcn_mfma_f32_16x16x32_bf16(af[mi], bfn[ni], ah[mi][ni], 0, 0, 0);
                }

            asm volatile("s_waitcnt lgkmcnt(0)" ::: "memory");
            __builtin_amdgcn_s_barrier();
            if (kt + 3 < nkt) stage(cur, kt + 3, t);
            cur = (cur == 2) ? 0 : cur + 1;
        }

        // prefetch next step's pass-1 tiles (x & Wih only; no h dependency)
        if (t + 1 < L) {
            stage(0, 0, t + 1); stage(1, 1, t + 1); stage(2, 2, t + 1);
        }

        // epilogue: gates -> hbo
        #pragma unroll
        for (int ni = 0; ni < 2; ++ni) {
            const int j = j0 + wn * 32 + ni * 16 + fr;
            const float bir = b_ih[j],         bhr = b_hh[j];
            const float biz = b_ih[H + j],     bhz = b_hh[H + j];
            const float bin = b_ih[2 * H + j], bhn = b_hh[2 * H + j];
            #pragma unroll
            for (int mi = 0; mi < 4; ++mi) {
                #pragma unroll
                for (int r = 0; r < 4; ++r) {
                    const int m = m0 + wm * 64 + mi * 16 + kg * 4 + r;
                    const float rg = sigf(ar[mi][ni][r] + bir + bhr);
                    const float zg = sigf(az[mi][ni][r] + biz + bhz);
                    const float ng = tanhf_fast(an[mi][ni][r] + bin + rg * (ah[mi][ni][r] + bhn));
                    const size_t off = (size_t)m * H + j;
                    const float hv = bf2f(hbi[off]);
                    hbo[off] = f2bf((1.f - zg) * ng + zg * hv);
                }
            }
        }

        if (t + 1 < L)
            grid_sync(&bar[0], &bar[1], gridDim.x, (unsigned)t);
    }
}

// ---------------------------------------------------------------------------
// m97-style GEMM, 3-deep pipeline: C[M][N](f32) = A(bf16) @ BT^T (+bias).
// ---------------------------------------------------------------------------
__global__ __launch_bounds__(256)
void mfma_gemm128(const unsigned short* __restrict__ A,
                  const unsigned short* __restrict__ BT,
                  const float* __restrict__ bias,
                  float* __restrict__ C, int M, int N, int K)
{
    const int m0 = blockIdx.x * 128, n0 = blockIdx.y * 128;
    const int tid = (int)threadIdx.x, lane = tid & 63, wid = tid >> 6;
    const int wm = wid >> 1, wn = wid & 1;
    const int fr = lane & 15, kg = lane >> 4;
    const int lrow = lane >> 2;
    const int scol = swz(lane & 3, lrow);

    __shared__ unsigned short smem[3 * 8192];

    f32x4 acc[4][4];
    #pragma unroll
    for (int i = 0; i < 4; ++i)
        #pragma unroll
        for (int j = 0; j < 4; ++j)
            acc[i][j] = (f32x4){0.f, 0.f, 0.f, 0.f};

    auto stage = [&](int buf, int kt) {
        const int k0 = kt * 32;
        unsigned short* base = &smem[buf * 8192];
        #pragma unroll
        for (int q = 0; q < 4; ++q) {
            const int c = wid * 4 + q;
            const unsigned short* g = (c < 8)
                ? A + (size_t)(m0 + c * 16 + lrow) * K + k0 + scol
                : BT + (size_t)(n0 + (c - 8) * 16 + lrow) * K + k0 + scol;
            gload16(g, base + c * 512);
        }
    };

    const int nkt = K >> 5;
    stage(0, 0); stage(1, 1); stage(2, 2);
    int cur = 0;

    for (int kt = 0; kt < nkt; ++kt) {
        if (kt + 2 < nkt)      asm volatile("s_waitcnt vmcnt(8)" ::: "memory");
        else if (kt + 1 < nkt) asm volatile("s_waitcnt vmcnt(4)" ::: "memory");
        else                   asm volatile("s_waitcnt vmcnt(0)" ::: "memory");
        __builtin_amdgcn_s_barrier();

        const unsigned short* sb = &smem[cur * 8192];
        bf16x8 af[4], bf[4];
        #pragma unroll
        for (int mi = 0; mi < 4; ++mi) {
            const int row = wm * 64 + mi * 16 + fr;
            af[mi] = *reinterpret_cast<const bf16x8*>(&sb[row * 32 + swz(kg, row)]);
        }
        #pragma unroll
        for (int ni = 0; ni < 4; ++ni) {
            const int row = wn * 64 + ni * 16 + fr;
            bf[ni] = *reinterpret_cast<const bf16x8*>(&sb[4096 + row * 32 + swz(kg, row)]);
        }
        #pragma unroll
        for (int mi = 0; mi < 4; ++mi)
            #pragma unroll
            for (int ni = 0; ni < 4; ++ni)
                acc[mi][ni] = __builtin_amdgcn_mfma_f32_16x16x32_bf16(
                    af[mi], bf[ni], acc[mi][ni], 0, 0, 0);

        asm volatile("s_waitcnt lgkmcnt(0)" ::: "memory");
        __builtin_amdgcn_s_barrier();
        if (kt + 3 < nkt) stage(cur, kt + 3);
        cur = (cur == 2) ? 0 : cur + 1;
    }

    #pragma unroll
    for (int ni = 0; ni < 4; ++ni) {
        const int n = n0 + wn * 64 + ni * 16 + fr;
        const float bv = bias ? bias[n] : 0.f;
        #pragma unroll
        for (int mi = 0; mi < 4; ++mi)
            #pragma unroll
            for (int r = 0; r < 4; ++r) {
                const int m = m0 + wm * 64 + mi * 16 + kg * 4 + r;
                C[(size_t)m * N + n] = acc[mi][ni][r] + bv;
            }
    }
}

// ---------------------------------------------------------------------------
// Fused tree phase: all D levels + gather in ONE kernel. Grid 256 blocks,
// load-spin grid barriers between phases.
// ---------------------------------------------------------------------------
__global__ __launch_bounds__(256, 1)
void tree_fused(unsigned short* __restrict__ hb,        // bf16 tree h (hb1)
                const unsigned short* __restrict__ UcombT,  // [2048][512]
                const float* __restrict__ xg,               // [N][2048]
                float* __restrict__ cT, float* __restrict__ hT,
                const int* __restrict__ parent,
                const int* __restrict__ root_ids,
                float* __restrict__ giou,                   // [PER][1536] (zeroed)
                float* __restrict__ fcs,                    // [PER][512]  (zeroed)
                float* __restrict__ out,
                int D, int PER, unsigned* __restrict__ bar)
{
    constexpr int H = 512, N4H = 2048, G3H = 1536;
    const int bx = (int)blockIdx.x, tid = (int)threadIdx.x;
    const int lane = tid & 63, wid = tid >> 6;
    const int wm = wid >> 1, wn = wid & 1;
    const int fr = lane & 15, kg = lane >> 4;
    const int lrow = lane >> 2;
    const int scol = swz(lane & 3, lrow);
    const int per_blk = PER * H / 256;    // 2048 elements per block

    __shared__ unsigned short smem[3 * 6144];

    unsigned my = 0;

    for (int lvl = D - 1; lvl >= 0; --lvl) {
        const int pstart = lvl * PER;
        const int cstart = (lvl + 1) * PER;

        if (lvl < D - 1) {
            const int m0 = (bx >> 4) * 64, n0 = (bx & 15) * 128;

            f32x4 acc[2][4];
            #pragma unroll
            for (int i = 0; i < 2; ++i)
                #pragma unroll
                for (int j = 0; j < 4; ++j)
                    acc[i][j] = (f32x4){0.f, 0.f, 0.f, 0.f};

            auto stage = [&](int buf, int kt) {
                const int k0 = kt * 32;
                unsigned short* base = &smem[buf * 6144];
                #pragma unroll
                for (int q = 0; q < 3; ++q) {
                    const int c = wid * 3 + q;   // 12 chunks
                    const unsigned short* g = (c < 4)
                        ? hb + (size_t)(cstart + m0 + c * 16 + lrow) * H + k0 + scol
                        : UcombT + (size_t)(n0 + (c - 4) * 16 + lrow) * H + k0 + scol;
                    gload16(g, base + c * 512);
                }
            };

            constexpr int nkt = H / 32;  // 16
            stage(0, 0); stage(1, 1); stage(2, 2);
            int cur = 0;

            for (int kt = 0; kt < nkt; ++kt) {
                if (kt + 2 < nkt)      asm volatile("s_waitcnt vmcnt(6)" ::: "memory");
                else if (kt + 1 < nkt) asm volatile("s_waitcnt vmcnt(3)" ::: "memory");
                else                   asm volatile("s_waitcnt vmcnt(0)" ::: "memory");
                __builtin_amdgcn_s_barrier();

                const unsigned short* sb = &smem[cur * 6144];
                bf16x8 af[2], bf[4];
                #pragma unroll
                for (int mi = 0; mi < 2; ++mi) {
                    const int row = wm * 32 + mi * 16 + fr;
                    af[mi] = *reinterpret_cast<const bf16x8*>(&sb[row * 32 + swz(kg, row)]);
                }
                #pragma unroll
                for (int ni = 0; ni < 4; ++ni) {
                    const int row = wn * 64 + ni * 16 + fr;
                    bf[ni] = *reinterpret_cast<const bf16x8*>(&sb[2048 + row * 32 + swz(kg, row)]);
                }
                #pragma unroll
                for (int mi = 0; mi < 2; ++mi)
                    #pragma unroll
                    for (int ni = 0; ni < 4; ++ni)
                        acc[mi][ni] = __builtin_amdgcn_mfma_f32_16x16x32_bf16(
                            af[mi], bf[ni], acc[mi][ni], 0, 0, 0);

                asm volatile("s_waitcnt lgkmcnt(0)" ::: "memory");
                __builtin_amdgcn_s_barrier();
                if (kt + 3 < nkt) stage(cur, kt + 3);
                cur = (cur == 2) ? 0 : cur + 1;
            }

            if (n0 < G3H) {
                #pragma unroll
                for (int mi = 0; mi < 2; ++mi)
                    #pragma unroll
                    for (int r = 0; r < 4; ++r) {
                        const int m = m0 + wm * 32 + mi * 16 + kg * 4 + r;
                        const int p = parent[cstart + m] - pstart;
                        #pragma unroll
                        for (int ni = 0; ni < 4; ++ni) {
                            const int n = n0 + wn * 64 + ni * 16 + fr;
                            atomicAdd(&giou[(size_t)p * G3H + n], acc[mi][ni][r]);
                        }
                    }
            } else {
                #pragma unroll
                for (int mi = 0; mi < 2; ++mi)
                    #pragma unroll
                    for (int r = 0; r < 4; ++r) {
                        const int m = m0 + wm * 32 + mi * 16 + kg * 4 + r;
                        const int child = cstart + m;
                        const int p = parent[child];
                        #pragma unroll
                        for (int ni = 0; ni < 4; ++ni) {
                            const int jf = n0 + wn * 64 + ni * 16 + fr - G3H;
                            const float f = sigf(acc[mi][ni][r] + xg[(size_t)p * N4H + G3H + jf]);
                            atomicAdd(&fcs[(size_t)(p - pstart) * H + jf],
                                      f * cT[(size_t)child * H + jf]);
                        }
                    }
            }
            grid_sync(&bar[0], &bar[1], gridDim.x, my++);
        }

        // ---- level update (exclusive slots; self-zeroes giou/fcs) ----
        #pragma unroll
        for (int e = 0; e < 8; ++e) {
            const int idx = bx * per_blk + e * 256 + tid;
            const int pi = idx >> 9, j = idx & (H - 1);
            const int p = pstart + pi;
            const size_t xb4 = (size_t)p * N4H;
            const size_t gb = (size_t)pi * G3H;
            const float ig = sigf(xg[xb4 + j] + giou[gb + j]);
            const float og = sigf(xg[xb4 + H + j] + giou[gb + H + j]);
            const float ug = tanhf_fast(xg[xb4 + 2 * H + j] + giou[gb + 2 * H + j]);
            const float cn = ig * ug + fcs[idx];
            const float hn = og * tanhf_fast(cn);
            const size_t off = (size_t)p * H + j;
            cT[off] = cn;
            hT[off] = hn;
            hb[off] = f2bf(hn);
            giou[gb + j] = 0.f;
            giou[gb + H + j] = 0.f;
            giou[gb + 2 * H + j] = 0.f;
            fcs[idx] = 0.f;
        }
        grid_sync(&bar[0], &bar[1], gridDim.x, my++);
    }

    // ---- gather roots ----
    #pragma unroll
    for (int e = 0; e < 8; ++e) {
        const int idx = bx * per_blk + e * 256 + tid;
        const int tt = idx >> 9, j = idx & (H - 1);
        const int rid = root_ids[tt];
        out[idx] = cT[(size_t)rid * H + j];
        out[(size_t)PER * H + idx] = hT[(size_t)rid * H + j];
    }
}

// ---------------------------------------------------------------------------
extern "C" void kernel_launch(void* const* d_in, const int* in_sizes, int n_in,
                              void* d_out, int out_size, void* d_ws, size_t ws_size,
                              hipStream_t stream)
{
    const float* x_seq = (const float*)d_in[0];
    const float* W_ih  = (const float*)d_in[1];
    const float* W_hh  = (const float*)d_in[2];
    const float* b_ih  = (const float*)d_in[3];
    const float* b_hh  = (const float*)d_in[4];
    const float* Wx    = (const float*)d_in[5];
    const float* bx    = (const float*)d_in[6];
    const float* U_iou = (const float*)d_in[7];
    const float* U_f   = (const float*)d_in[8];
    const int* parent  = (const int*)d_in[9];
    const int* root_ids = (const int*)d_in[11];

    const int threeH = in_sizes[3];          // 1536
    const int H   = threeH / 3;              // 512
    const int I   = in_sizes[1] / threeH;    // 256
    const int N   = in_sizes[9];             // 8192
    const int L   = in_sizes[0] / (N * I);   // 8
    const int PER = in_sizes[11];            // 1024
    const int D   = N / PER;                 // 8

    const size_t NH = (size_t)N * H;
    const size_t PH = (size_t)PER * H;

    // ---- workspace carve-up (xb aliases xg: xb dead before xg written) ----
    char* p = (char*)d_ws;
    const size_t zone_sz = ((size_t)N * 4 * H * 4 > (size_t)N * L * I * 2)
                         ? (size_t)N * 4 * H * 4 : (size_t)N * L * I * 2;
    unsigned short* xb = (unsigned short*)p;
    float* xg = (float*)p;                       p += zone_sz;
    unsigned short* hb0 = (unsigned short*)p;    p += NH * 2;
    unsigned short* hb1 = (unsigned short*)p;    p += NH * 2;
    float* cT = (float*)p;                       p += NH * 4;
    float* hT = (float*)p;                       p += NH * 4;
    unsigned short* WihT = (unsigned short*)p;   p += (size_t)threeH * I * 2;
    unsigned short* WhhT = (unsigned short*)p;   p += (size_t)threeH * H * 2;
    unsigned short* WxT  = (unsigned short*)p;   p += (size_t)4 * H * H * 2;
    unsigned short* UcombT = (unsigned short*)p; p += (size_t)4 * H * H * 2;
    float* giou = (float*)p;                     p += PH * 3 * 4;
    float* fcs  = (float*)p;                     p += PH * 4;   // adjacent to giou
    unsigned* bar = (unsigned*)p;                p += 512;      // sync cells
    if ((size_t)(p - (char*)d_ws) > ws_size) return;

    // ---- prep ----
    {
        const int n = N * L * I;
        cvt_f32_bf16<<<(n / 4 + 255) / 256, 256, 0, stream>>>(x_seq, xb, n);
        dim3 blk(32, 8);
        transpose_cvt<<<dim3(threeH / 32, I / 32), blk, 0, stream>>>(W_ih, WihT, I, threeH);
        transpose_cvt<<<dim3(threeH / 32, H / 32), blk, 0, stream>>>(W_hh, WhhT, H, threeH);
        transpose_cvt<<<dim3(4 * H / 32, H / 32), blk, 0, stream>>>(Wx, WxT, H, 4 * H);
        transpose_cvt<<<dim3(threeH / 32, H / 32), blk, 0, stream>>>(U_iou, UcombT, H, threeH);
        transpose_cvt<<<dim3(H / 32, H / 32), blk, 0, stream>>>(
            U_f, UcombT + (size_t)threeH * H, H, H);
    }
    hipMemsetAsync(hb0, 0, NH * 2, stream);
    hipMemsetAsync(giou, 0, PH * 4 * 4, stream);   // giou + fcs once
    hipMemsetAsync(bar, 0, 512, stream);           // barrier state (per launch!)

    // ---- Phase 1: fused GRU (512 blocks = 2/CU, co-resident) ----
    gru_fused<<<(N / 128) * (H / 64), 256, 0, stream>>>(
        xb, WihT, WhhT, b_ih, b_hh, hb0, hb1, L, bar);
    // L even -> enc bf16 in hb0

    // ---- Phase 2: xg = enc @ Wx + bx ----
    mfma_gemm128<<<dim3(N / 128, 4 * H / 128), 256, 0, stream>>>(
        hb0, WxT, bx, xg, N, 4 * H, H);

    // ---- Phase 3+4: fused tree + gather (256 blocks = 1/CU) ----
    tree_fused<<<256, 256, 0, stream>>>(hb1, UcombT, xg, cT, hT, parent,
                                        root_ids, giou, fcs, (float*)d_out,
                                        D, PER, bar + 64);
}

// Round 9
// 520.101 us; speedup vs baseline: 3.1326x; 3.1326x over previous
//
#include <hip/hip_runtime.h>
#include <math.h>

typedef short bf16x8 __attribute__((ext_vector_type(8)));
typedef float f32x4 __attribute__((ext_vector_type(4)));

__device__ __forceinline__ float sigf(float x) {
    return __builtin_amdgcn_rcpf(1.f + __expf(-x));
}
__device__ __forceinline__ float tanhf_fast(float x) {
    const float e = __expf(2.f * x);
    return 1.f - 2.f * __builtin_amdgcn_rcpf(e + 1.f);
}

__device__ __forceinline__ unsigned short f2bf(float f) {
    union { float f; unsigned u; } v; v.f = f;
    unsigned r = (v.u + 0x7FFFu + ((v.u >> 16) & 1u)) >> 16;
    return (unsigned short)r;
}
__device__ __forceinline__ float bf2f(unsigned short u) {
    union { unsigned u; float f; } v; v.u = ((unsigned)u) << 16; return v.f;
}

// async global->LDS, 16B per lane; LDS dest = wave-uniform base + lane*16B.
__device__ __forceinline__ void gload16(const unsigned short* g, unsigned short* l) {
    __builtin_amdgcn_global_load_lds(
        (const __attribute__((address_space(1))) void*)g,
        (__attribute__((address_space(3))) void*)l, 16, 0, 0);
}

// Chunk = 16 rows x 32 ushorts (1 KiB). Lane i -> (row=i>>2, slot=i&3).
// Both-sides bank swizzle: source col = (slot ^ ((row>>1)&3))*8; LDS linear;
// reads use the same XOR. (row>>1)&3 is chunk-index-invariant since chunks
// are 16 rows.
__device__ __forceinline__ int swz(int slot, int row) {
    return (slot ^ ((row >> 1) & 3)) * 8;
}

// ---------------------------------------------------------------------------
// prep kernels
// ---------------------------------------------------------------------------
__global__ void cvt_f32_bf16(const float* __restrict__ src,
                             unsigned short* __restrict__ dst, int n)
{
    const int i = (blockIdx.x * blockDim.x + threadIdx.x) * 4;
    if (i >= n) return;
    const float4 v = *reinterpret_cast<const float4*>(src + i);
    ushort4 o;
    o.x = f2bf(v.x); o.y = f2bf(v.y); o.z = f2bf(v.z); o.w = f2bf(v.w);
    *reinterpret_cast<ushort4*>(dst + i) = o;
}

__global__ void transpose_cvt(const float* __restrict__ src,
                              unsigned short* __restrict__ dst,
                              int rows, int cols)
{
    __shared__ float tile[32][33];
    const int bc = blockIdx.x * 32, br = blockIdx.y * 32;
    const int tx = threadIdx.x, ty = threadIdx.y;  // block (32,8)
    #pragma unroll
    for (int i = 0; i < 32; i += 8)
        tile[ty + i][tx] = src[(size_t)(br + ty + i) * cols + bc + tx];
    __syncthreads();
    #pragma unroll
    for (int i = 0; i < 32; i += 8)
        dst[(size_t)(bc + ty + i) * rows + br + tx] = f2bf(tile[tx][ty + i]);
}

// ---------------------------------------------------------------------------
// Fused MFMA GRU step, 64x64 tile for 4 blocks/CU occupancy (16 waves/CU).
// Grid dim3(N/64, H/64) = (128, 8): consecutive blockIdx.x share B-weights;
// blocks sharing an A-tile (same x, 8 y's) are 128 apart -> same XCD.
// 4 waves 2x2, wave tile 32x32. 2-buffer 2-deep counted-vmcnt pipeline.
// Per buffer: A[64][32] @ 0, B[3][64][32] @ 2048 (8192 ushorts, 16 KiB).
// Each wave stages 4 chunks/tile -> wait vmcnt(4) steady-state, 0 at tail.
// ---------------------------------------------------------------------------
__global__ __launch_bounds__(256, 4)
void gru_mfma(const unsigned short* __restrict__ xb, int t,
              const unsigned short* __restrict__ hbi,
              unsigned short* __restrict__ hbo,
              const unsigned short* __restrict__ WihT,
              const unsigned short* __restrict__ WhhT,
              const float* __restrict__ b_ih, const float* __restrict__ b_hh)
{
    constexpr int I = 256, H = 512, LI = 2048;
    const int m0 = blockIdx.x * 64, j0 = blockIdx.y * 64;
    const int tid = (int)threadIdx.x, lane = tid & 63, wid = tid >> 6;
    const int wm = wid >> 1, wn = wid & 1;
    const int fr = lane & 15, kg = lane >> 4;
    const int lrow = lane >> 2;
    const int scol = swz(lane & 3, lrow);

    __shared__ unsigned short smem[2 * 8192];

    f32x4 ar[2][2], az[2][2], an[2][2], ah[2][2];
    #pragma unroll
    for (int i = 0; i < 2; ++i)
        #pragma unroll
        for (int j = 0; j < 2; ++j) {
            ar[i][j] = (f32x4){0.f, 0.f, 0.f, 0.f};
            az[i][j] = (f32x4){0.f, 0.f, 0.f, 0.f};
            an[i][j] = (f32x4){0.f, 0.f, 0.f, 0.f};
            ah[i][j] = (f32x4){0.f, 0.f, 0.f, 0.f};
        }

    constexpr int nkt1 = I / 32;          // 8
    constexpr int nkt = (I + H) / 32;     // 24

    auto stage = [&](int buf, int kt) {
        const bool s1 = (kt < nkt1);
        const int k0 = s1 ? kt * 32 : (kt - nkt1) * 32;
        unsigned short* base = &smem[buf * 8192];
        #pragma unroll
        for (int q = 0; q < 4; ++q) {
            const int c = wid * 4 + q;     // 16 chunks of 1 KiB
            if (c < 4) {
                const int row = c * 16 + lrow;
                const unsigned short* g = s1
                    ? xb + (size_t)(m0 + row) * LI + t * I + k0 + scol
                    : hbi + (size_t)(m0 + row) * H + k0 + scol;
                gload16(g, base + c * 512);
            } else {
                const int bc = c - 4, gi = bc >> 2;        // gate 0..2
                const int row = (bc & 3) * 16 + lrow;
                const unsigned short* g = s1
                    ? WihT + (size_t)(gi * H + j0 + row) * I + k0 + scol
                    : WhhT + (size_t)(gi * H + j0 + row) * H + k0 + scol;
                gload16(g, base + c * 512);
            }
        }
    };

    stage(0, 0); stage(1, 1);

    for (int kt = 0; kt < nkt; ++kt) {
        if (kt + 1 < nkt) asm volatile("s_waitcnt vmcnt(4)" ::: "memory");
        else              asm volatile("s_waitcnt vmcnt(0)" ::: "memory");
        __builtin_amdgcn_s_barrier();

        const unsigned short* sb = &smem[(kt & 1) * 8192];
        bf16x8 af[2], bfr[2], bfz[2], bfn[2];
        #pragma unroll
        for (int mi = 0; mi < 2; ++mi) {
            const int row = wm * 32 + mi * 16 + fr;
            af[mi] = *reinterpret_cast<const bf16x8*>(&sb[row * 32 + swz(kg, row)]);
        }
        #pragma unroll
        for (int ni = 0; ni < 2; ++ni) {
            const int row = wn * 32 + ni * 16 + fr;
            const int sw = swz(kg, row);
            bfr[ni] = *reinterpret_cast<const bf16x8*>(&sb[2048 + (row) * 32 + sw]);
            bfz[ni] = *reinterpret_cast<const bf16x8*>(&sb[2048 + (64 + row) * 32 + sw]);
            bfn[ni] = *reinterpret_cast<const bf16x8*>(&sb[2048 + (128 + row) * 32 + sw]);
        }
        const bool p1 = (kt < nkt1);
        #pragma unroll
        for (int mi = 0; mi < 2; ++mi)
            #pragma unroll
            for (int ni = 0; ni < 2; ++ni) {
                ar[mi][ni] = __builtin_amdgcn_mfma_f32_16x16x32_bf16(af[mi], bfr[ni], ar[mi][ni], 0, 0, 0);
                az[mi][ni] = __builtin_amdgcn_mfma_f32_16x16x32_bf16(af[mi], bfz[ni], az[mi][ni], 0, 0, 0);
                if (p1)
                    an[mi][ni] = __builtin_amdgcn_mfma_f32_16x16x32_bf16(af[mi], bfn[ni], an[mi][ni], 0, 0, 0);
                else
                    ah[mi][ni] = __builtin_amdgcn_mfma_f32_16x16x32_bf16(af[mi], bfn[ni], ah[mi][ni], 0, 0, 0);
            }

        asm volatile("s_waitcnt lgkmcnt(0)" ::: "memory");
        __builtin_amdgcn_s_barrier();
        if (kt + 2 < nkt) stage(kt & 1, kt + 2);
    }

    #pragma unroll
    for (int ni = 0; ni < 2; ++ni) {
        const int j = j0 + wn * 32 + ni * 16 + fr;
        const float bir = b_ih[j],         bhr = b_hh[j];
        const float biz = b_ih[H + j],     bhz = b_hh[H + j];
        const float bin = b_ih[2 * H + j], bhn = b_hh[2 * H + j];
        #pragma unroll
        for (int mi = 0; mi < 2; ++mi) {
            #pragma unroll
            for (int r = 0; r < 4; ++r) {
                const int m = m0 + wm * 32 + mi * 16 + kg * 4 + r;
                const float rg = sigf(ar[mi][ni][r] + bir + bhr);
                const float zg = sigf(az[mi][ni][r] + biz + bhz);
                const float ng = tanhf_fast(an[mi][ni][r] + bin + rg * (ah[mi][ni][r] + bhn));
                const size_t off = (size_t)m * H + j;
                const float hv = bf2f(hbi[off]);
                hbo[off] = f2bf((1.f - zg) * ng + zg * hv);
            }
        }
    }
}

// ---------------------------------------------------------------------------
// m97-style GEMM, 3-deep pipeline: C[M][N](f32) = A(bf16) @ BT^T (+bias).
// ---------------------------------------------------------------------------
__global__ __launch_bounds__(256)
void mfma_gemm128(const unsigned short* __restrict__ A,
                  const unsigned short* __restrict__ BT,
                  const float* __restrict__ bias,
                  float* __restrict__ C, int M, int N, int K)
{
    const int m0 = blockIdx.x * 128, n0 = blockIdx.y * 128;
    const int tid = (int)threadIdx.x, lane = tid & 63, wid = tid >> 6;
    const int wm = wid >> 1, wn = wid & 1;
    const int fr = lane & 15, kg = lane >> 4;
    const int lrow = lane >> 2;
    const int scol = swz(lane & 3, lrow);

    __shared__ unsigned short smem[3 * 8192];

    f32x4 acc[4][4];
    #pragma unroll
    for (int i = 0; i < 4; ++i)
        #pragma unroll
        for (int j = 0; j < 4; ++j)
            acc[i][j] = (f32x4){0.f, 0.f, 0.f, 0.f};

    auto stage = [&](int buf, int kt) {
        const int k0 = kt * 32;
        unsigned short* base = &smem[buf * 8192];
        #pragma unroll
        for (int q = 0; q < 4; ++q) {
            const int c = wid * 4 + q;
            const unsigned short* g = (c < 8)
                ? A + (size_t)(m0 + c * 16 + lrow) * K + k0 + scol
                : BT + (size_t)(n0 + (c - 8) * 16 + lrow) * K + k0 + scol;
            gload16(g, base + c * 512);
        }
    };

    const int nkt = K >> 5;
    stage(0, 0); stage(1, 1); stage(2, 2);
    int cur = 0;

    for (int kt = 0; kt < nkt; ++kt) {
        if (kt + 2 < nkt)      asm volatile("s_waitcnt vmcnt(8)" ::: "memory");
        else if (kt + 1 < nkt) asm volatile("s_waitcnt vmcnt(4)" ::: "memory");
        else                   asm volatile("s_waitcnt vmcnt(0)" ::: "memory");
        __builtin_amdgcn_s_barrier();

        const unsigned short* sb = &smem[cur * 8192];
        bf16x8 af[4], bf[4];
        #pragma unroll
        for (int mi = 0; mi < 4; ++mi) {
            const int row = wm * 64 + mi * 16 + fr;
            af[mi] = *reinterpret_cast<const bf16x8*>(&sb[row * 32 + swz(kg, row)]);
        }
        #pragma unroll
        for (int ni = 0; ni < 4; ++ni) {
            const int row = wn * 64 + ni * 16 + fr;
            bf[ni] = *reinterpret_cast<const bf16x8*>(&sb[4096 + row * 32 + swz(kg, row)]);
        }
        #pragma unroll
        for (int mi = 0; mi < 4; ++mi)
            #pragma unroll
            for (int ni = 0; ni < 4; ++ni)
                acc[mi][ni] = __builtin_amdgcn_mfma_f32_16x16x32_bf16(
                    af[mi], bf[ni], acc[mi][ni], 0, 0, 0);

        asm volatile("s_waitcnt lgkmcnt(0)" ::: "memory");
        __builtin_amdgcn_s_barrier();
        if (kt + 3 < nkt) stage(cur, kt + 3);
        cur = (cur == 2) ? 0 : cur + 1;
    }

    #pragma unroll
    for (int ni = 0; ni < 4; ++ni) {
        const int n = n0 + wn * 64 + ni * 16 + fr;
        const float bv = bias ? bias[n] : 0.f;
        #pragma unroll
        for (int mi = 0; mi < 4; ++mi)
            #pragma unroll
            for (int r = 0; r < 4; ++r) {
                const int m = m0 + wm * 64 + mi * 16 + kg * 4 + r;
                C[(size_t)m * N + n] = acc[mi][ni][r] + bv;
            }
    }
}

// ---------------------------------------------------------------------------
// Tree level mega-GEMM, 3-deep pipeline: G = h_c @ [U_iou | U_f].
// Epilogue scatters to giou (atomic) / fcs (f=sig(G+xf[parent]), atomic).
// ---------------------------------------------------------------------------
__global__ __launch_bounds__(256)
void tree_gemm(const unsigned short* __restrict__ hTb,
               const unsigned short* __restrict__ UcombT,  // [2048][512]
               const float* __restrict__ xg,               // [N][2048]
               const float* __restrict__ cT,               // [N][512]
               const int* __restrict__ parent,
               int cstart, int pstart,
               float* __restrict__ giou,                   // [PER][1536]
               float* __restrict__ fcs)                    // [PER][512]
{
    constexpr int H = 512, N4H = 2048, G3H = 1536;
    const int m0 = blockIdx.x * 64, n0 = blockIdx.y * 128;
    const int tid = (int)threadIdx.x, lane = tid & 63, wid = tid >> 6;
    const int wm = wid >> 1, wn = wid & 1;
    const int fr = lane & 15, kg = lane >> 4;
    const int lrow = lane >> 2;
    const int scol = swz(lane & 3, lrow);

    __shared__ unsigned short smem[3 * 6144];

    f32x4 acc[2][4];
    #pragma unroll
    for (int i = 0; i < 2; ++i)
        #pragma unroll
        for (int j = 0; j < 4; ++j)
            acc[i][j] = (f32x4){0.f, 0.f, 0.f, 0.f};

    auto stage = [&](int buf, int kt) {
        const int k0 = kt * 32;
        unsigned short* base = &smem[buf * 6144];
        #pragma unroll
        for (int q = 0; q < 3; ++q) {
            const int c = wid * 3 + q;   // 12 chunks
            const unsigned short* g = (c < 4)
                ? hTb + (size_t)(cstart + m0 + c * 16 + lrow) * H + k0 + scol
                : UcombT + (size_t)(n0 + (c - 4) * 16 + lrow) * H + k0 + scol;
            gload16(g, base + c * 512);
        }
    };

    constexpr int nkt = H / 32;  // 16
    stage(0, 0); stage(1, 1); stage(2, 2);
    int cur = 0;

    for (int kt = 0; kt < nkt; ++kt) {
        if (kt + 2 < nkt)      asm volatile("s_waitcnt vmcnt(6)" ::: "memory");
        else if (kt + 1 < nkt) asm volatile("s_waitcnt vmcnt(3)" ::: "memory");
        else                   asm volatile("s_waitcnt vmcnt(0)" ::: "memory");
        __builtin_amdgcn_s_barrier();

        const unsigned short* sb = &smem[cur * 6144];
        bf16x8 af[2], bf[4];
        #pragma unroll
        for (int mi = 0; mi < 2; ++mi) {
            const int row = wm * 32 + mi * 16 + fr;
            af[mi] = *reinterpret_cast<const bf16x8*>(&sb[row * 32 + swz(kg, row)]);
        }
        #pragma unroll
        for (int ni = 0; ni < 4; ++ni) {
            const int row = wn * 64 + ni * 16 + fr;
            bf[ni] = *reinterpret_cast<const bf16x8*>(&sb[2048 + row * 32 + swz(kg, row)]);
        }
        #pragma unroll
        for (int mi = 0; mi < 2; ++mi)
            #pragma unroll
            for (int ni = 0; ni < 4; ++ni)
                acc[mi][ni] = __builtin_amdgcn_mfma_f32_16x16x32_bf16(
                    af[mi], bf[ni], acc[mi][ni], 0, 0, 0);

        asm volatile("s_waitcnt lgkmcnt(0)" ::: "memory");
        __builtin_amdgcn_s_barrier();
        if (kt + 3 < nkt) stage(cur, kt + 3);
        cur = (cur == 2) ? 0 : cur + 1;
    }

    if (n0 < G3H) {
        #pragma unroll
        for (int mi = 0; mi < 2; ++mi)
            #pragma unroll
            for (int r = 0; r < 4; ++r) {
                const int m = m0 + wm * 32 + mi * 16 + kg * 4 + r;
                const int p = parent[cstart + m] - pstart;
                #pragma unroll
                for (int ni = 0; ni < 4; ++ni) {
                    const int n = n0 + wn * 64 + ni * 16 + fr;
                    atomicAdd(&giou[(size_t)p * G3H + n], acc[mi][ni][r]);
                }
            }
    } else {
        #pragma unroll
        for (int mi = 0; mi < 2; ++mi)
            #pragma unroll
            for (int r = 0; r < 4; ++r) {
                const int m = m0 + wm * 32 + mi * 16 + kg * 4 + r;
                const int child = cstart + m;
                const int p = parent[child];
                #pragma unroll
                for (int ni = 0; ni < 4; ++ni) {
                    const int jf = n0 + wn * 64 + ni * 16 + fr - G3H;
                    const float f = sigf(acc[mi][ni][r] + xg[(size_t)p * N4H + G3H + jf]);
                    atomicAdd(&fcs[(size_t)(p - pstart) * H + jf],
                              f * cT[(size_t)child * H + jf]);
                }
            }
    }
}

// ---------------------------------------------------------------------------
// level update; re-zeros exactly the giou/fcs slots it read (exclusive
// ownership) so no per-level memset is needed.
// ---------------------------------------------------------------------------
__global__ void level_update(const float* __restrict__ xg,
                             float* __restrict__ giou,
                             float* __restrict__ fcs,
                             float* __restrict__ cT, float* __restrict__ hT,
                             unsigned short* __restrict__ hb, int pstart)
{
    constexpr int H = 512, N4H = 2048, G3H = 1536;
    const int idx = blockIdx.x * blockDim.x + threadIdx.x;  // PER*H exact
    const int pi = idx >> 9, j = idx & (H - 1);
    const int p = pstart + pi;
    const size_t xb4 = (size_t)p * N4H;
    const size_t gb = (size_t)pi * G3H;
    const float ig = sigf(xg[xb4 + j] + giou[gb + j]);
    const float og = sigf(xg[xb4 + H + j] + giou[gb + H + j]);
    const float ug = tanhf_fast(xg[xb4 + 2 * H + j] + giou[gb + 2 * H + j]);
    const float cn = ig * ug + fcs[idx];
    const float hn = og * tanhf_fast(cn);
    const size_t off = (size_t)p * H + j;
    cT[off] = cn;
    hT[off] = hn;
    hb[off] = f2bf(hn);
    giou[gb + j] = 0.f;
    giou[gb + H + j] = 0.f;
    giou[gb + 2 * H + j] = 0.f;
    fcs[idx] = 0.f;
}

__global__ void gather_out_kernel(const float* __restrict__ c,
                                  const float* __restrict__ h,
                                  const int* __restrict__ root_ids,
                                  int nroot, float* __restrict__ out)
{
    constexpr int H = 512;
    const int idx = blockIdx.x * blockDim.x + threadIdx.x;  // nroot*H exact
    const int t = idx >> 9, j = idx & (H - 1);
    const int rid = root_ids[t];
    out[idx] = c[(size_t)rid * H + j];
    out[(size_t)nroot * H + idx] = h[(size_t)rid * H + j];
}

// ---------------------------------------------------------------------------
extern "C" void kernel_launch(void* const* d_in, const int* in_sizes, int n_in,
                              void* d_out, int out_size, void* d_ws, size_t ws_size,
                              hipStream_t stream)
{
    const float* x_seq = (const float*)d_in[0];
    const float* W_ih  = (const float*)d_in[1];
    const float* W_hh  = (const float*)d_in[2];
    const float* b_ih  = (const float*)d_in[3];
    const float* b_hh  = (const float*)d_in[4];
    const float* Wx    = (const float*)d_in[5];
    const float* bx    = (const float*)d_in[6];
    const float* U_iou = (const float*)d_in[7];
    const float* U_f   = (const float*)d_in[8];
    const int* parent  = (const int*)d_in[9];
    const int* root_ids = (const int*)d_in[11];

    const int threeH = in_sizes[3];          // 1536
    const int H   = threeH / 3;              // 512
    const int I   = in_sizes[1] / threeH;    // 256
    const int N   = in_sizes[9];             // 8192
    const int L   = in_sizes[0] / (N * I);   // 8
    const int PER = in_sizes[11];            // 1024
    const int D   = N / PER;                 // 8

    const size_t NH = (size_t)N * H;
    const size_t PH = (size_t)PER * H;

    // ---- workspace carve-up (xb aliases xg: xb dead before xg written) ----
    char* p = (char*)d_ws;
    const size_t zone_sz = ((size_t)N * 4 * H * 4 > (size_t)N * L * I * 2)
                         ? (size_t)N * 4 * H * 4 : (size_t)N * L * I * 2;
    unsigned short* xb = (unsigned short*)p;
    float* xg = (float*)p;                       p += zone_sz;
    unsigned short* hb0 = (unsigned short*)p;    p += NH * 2;
    unsigned short* hb1 = (unsigned short*)p;    p += NH * 2;
    float* cT = (float*)p;                       p += NH * 4;
    float* hT = (float*)p;                       p += NH * 4;
    unsigned short* WihT = (unsigned short*)p;   p += (size_t)threeH * I * 2;
    unsigned short* WhhT = (unsigned short*)p;   p += (size_t)threeH * H * 2;
    unsigned short* WxT  = (unsigned short*)p;   p += (size_t)4 * H * H * 2;
    unsigned short* UcombT = (unsigned short*)p; p += (size_t)4 * H * H * 2;
    float* giou = (float*)p;                     p += PH * 3 * 4;
    float* fcs  = (float*)p;                     p += PH * 4;   // adjacent to giou
    if ((size_t)(p - (char*)d_ws) > ws_size) return;

    // ---- prep ----
    {
        const int n = N * L * I;
        cvt_f32_bf16<<<(n / 4 + 255) / 256, 256, 0, stream>>>(x_seq, xb, n);
        dim3 blk(32, 8);
        transpose_cvt<<<dim3(threeH / 32, I / 32), blk, 0, stream>>>(W_ih, WihT, I, threeH);
        transpose_cvt<<<dim3(threeH / 32, H / 32), blk, 0, stream>>>(W_hh, WhhT, H, threeH);
        transpose_cvt<<<dim3(4 * H / 32, H / 32), blk, 0, stream>>>(Wx, WxT, H, 4 * H);
        transpose_cvt<<<dim3(threeH / 32, H / 32), blk, 0, stream>>>(U_iou, UcombT, H, threeH);
        transpose_cvt<<<dim3(H / 32, H / 32), blk, 0, stream>>>(
            U_f, UcombT + (size_t)threeH * H, H, H);
    }
    hipMemsetAsync(hb0, 0, NH * 2, stream);
    hipMemsetAsync(giou, 0, PH * 4 * 4, stream);   // giou + fcs once

    // ---- Phase 1: GRU (bf16 state ping-pong), 64x64 tiles, 1024 blocks ----
    {
        dim3 grid(N / 64, H / 64);
        for (int t = 0; t < L; ++t) {
            const unsigned short* hin = (t & 1) ? hb1 : hb0;
            unsigned short* hout = (t & 1) ? hb0 : hb1;
            gru_mfma<<<grid, 256, 0, stream>>>(xb, t, hin, hout,
                                               WihT, WhhT, b_ih, b_hh);
        }
        // L even -> enc bf16 in hb0
    }

    // ---- Phase 2: xg = enc @ Wx + bx ----
    mfma_gemm128<<<dim3(N / 128, 4 * H / 128), 256, 0, stream>>>(
        hb0, WxT, bx, xg, N, 4 * H, H);

    // ---- Phase 3: tree levels (deepest -> roots) ----
    unsigned short* hTb = hb1;  // tree h (bf16), free after GRU
    const int pw_blocks = (int)(PH / 256);

    for (int lvl = D - 1; lvl >= 0; --lvl) {
        const int pstart = lvl * PER;
        const int cstart = (lvl + 1) * PER;

        if (lvl < D - 1)
            tree_gemm<<<dim3(PER / 64, (4 * H) / 128), 256, 0, stream>>>(
                hTb, UcombT, xg, cT, parent, cstart, pstart, giou, fcs);

        level_update<<<pw_blocks, 256, 0, stream>>>(xg, giou, fcs, cT, hT,
                                                    hTb, pstart);
    }

    // ---- Phase 4: gather roots ----
    gather_out_kernel<<<pw_blocks, 256, 0, stream>>>(cT, hT, root_ids, PER,
                                                     (float*)d_out);
}

// Round 10
// 504.016 us; speedup vs baseline: 3.2326x; 1.0319x over previous
//
#include <hip/hip_runtime.h>
#include <math.h>

typedef short bf16x8 __attribute__((ext_vector_type(8)));
typedef float f32x4 __attribute__((ext_vector_type(4)));

__device__ __forceinline__ float sigf(float x) {
    return __builtin_amdgcn_rcpf(1.f + __expf(-x));
}
__device__ __forceinline__ float tanhf_fast(float x) {
    const float e = __expf(2.f * x);
    return 1.f - 2.f * __builtin_amdgcn_rcpf(e + 1.f);
}

__device__ __forceinline__ unsigned short f2bf(float f) {
    union { float f; unsigned u; } v; v.f = f;
    unsigned r = (v.u + 0x7FFFu + ((v.u >> 16) & 1u)) >> 16;
    return (unsigned short)r;
}
__device__ __forceinline__ float bf2f(unsigned short u) {
    union { unsigned u; float f; } v; v.u = ((unsigned)u) << 16; return v.f;
}

// async global->LDS, 16B per lane; LDS dest = wave-uniform base + lane*16B.
__device__ __forceinline__ void gload16(const unsigned short* g, unsigned short* l) {
    __builtin_amdgcn_global_load_lds(
        (const __attribute__((address_space(1))) void*)g,
        (__attribute__((address_space(3))) void*)l, 16, 0, 0);
}

// Chunk = 16 rows x 32 ushorts (1 KiB). Lane i -> (row=i>>2, slot=i&3).
// Both-sides bank swizzle: source col = (slot ^ ((row>>1)&3))*8; LDS linear;
// reads use the same XOR.
__device__ __forceinline__ int swz(int slot, int row) {
    return (slot ^ ((row >> 1) & 3)) * 8;
}

// ---------------------------------------------------------------------------
// prep kernels
// ---------------------------------------------------------------------------
__global__ void cvt_f32_bf16(const float* __restrict__ src,
                             unsigned short* __restrict__ dst, int n)
{
    const int i = (blockIdx.x * blockDim.x + threadIdx.x) * 4;
    if (i >= n) return;
    const float4 v = *reinterpret_cast<const float4*>(src + i);
    ushort4 o;
    o.x = f2bf(v.x); o.y = f2bf(v.y); o.z = f2bf(v.z); o.w = f2bf(v.w);
    *reinterpret_cast<ushort4*>(dst + i) = o;
}

__global__ void transpose_cvt(const float* __restrict__ src,
                              unsigned short* __restrict__ dst,
                              int rows, int cols)
{
    __shared__ float tile[32][33];
    const int bc = blockIdx.x * 32, br = blockIdx.y * 32;
    const int tx = threadIdx.x, ty = threadIdx.y;  // block (32,8)
    #pragma unroll
    for (int i = 0; i < 32; i += 8)
        tile[ty + i][tx] = src[(size_t)(br + ty + i) * cols + bc + tx];
    __syncthreads();
    #pragma unroll
    for (int i = 0; i < 32; i += 8)
        dst[(size_t)(bc + ty + i) * rows + br + tx] = f2bf(tile[tx][ty + i]);
}

// ---------------------------------------------------------------------------
// Fused MFMA GRU step, 64x64 tile, 4 blocks/CU. Phase order: vmcnt -> bar ->
// ds_read -> lgkm(0) -> bar -> STAGE (overlaps MFMA) -> setprio(1) MFMA.
// 2-buffer 2-deep counted vmcnt; 4 chunks/wave/tile -> vmcnt(4)/0.
// ---------------------------------------------------------------------------
__global__ __launch_bounds__(256, 4)
void gru_mfma(const unsigned short* __restrict__ xb, int t,
              const unsigned short* __restrict__ hbi,
              unsigned short* __restrict__ hbo,
              const unsigned short* __restrict__ WihT,
              const unsigned short* __restrict__ WhhT,
              const float* __restrict__ b_ih, const float* __restrict__ b_hh)
{
    constexpr int I = 256, H = 512, LI = 2048;
    const int m0 = blockIdx.x * 64, j0 = blockIdx.y * 64;
    const int tid = (int)threadIdx.x, lane = tid & 63, wid = tid >> 6;
    const int wm = wid >> 1, wn = wid & 1;
    const int fr = lane & 15, kg = lane >> 4;
    const int lrow = lane >> 2;
    const int scol = swz(lane & 3, lrow);

    __shared__ unsigned short smem[2 * 8192];

    f32x4 ar[2][2], az[2][2], an[2][2], ah[2][2];
    #pragma unroll
    for (int i = 0; i < 2; ++i)
        #pragma unroll
        for (int j = 0; j < 2; ++j) {
            ar[i][j] = (f32x4){0.f, 0.f, 0.f, 0.f};
            az[i][j] = (f32x4){0.f, 0.f, 0.f, 0.f};
            an[i][j] = (f32x4){0.f, 0.f, 0.f, 0.f};
            ah[i][j] = (f32x4){0.f, 0.f, 0.f, 0.f};
        }

    constexpr int nkt1 = I / 32;          // 8
    constexpr int nkt = (I + H) / 32;     // 24

    auto stage = [&](int buf, int kt) {
        const bool s1 = (kt < nkt1);
        const int k0 = s1 ? kt * 32 : (kt - nkt1) * 32;
        unsigned short* base = &smem[buf * 8192];
        #pragma unroll
        for (int q = 0; q < 4; ++q) {
            const int c = wid * 4 + q;     // 16 chunks of 1 KiB
            if (c < 4) {
                const int row = c * 16 + lrow;
                const unsigned short* g = s1
                    ? xb + (size_t)(m0 + row) * LI + t * I + k0 + scol
                    : hbi + (size_t)(m0 + row) * H + k0 + scol;
                gload16(g, base + c * 512);
            } else {
                const int bc = c - 4, gi = bc >> 2;        // gate 0..2
                const int row = (bc & 3) * 16 + lrow;
                const unsigned short* g = s1
                    ? WihT + (size_t)(gi * H + j0 + row) * I + k0 + scol
                    : WhhT + (size_t)(gi * H + j0 + row) * H + k0 + scol;
                gload16(g, base + c * 512);
            }
        }
    };

    stage(0, 0); stage(1, 1);

    for (int kt = 0; kt < nkt; ++kt) {
        if (kt + 1 < nkt) asm volatile("s_waitcnt vmcnt(4)" ::: "memory");
        else              asm volatile("s_waitcnt vmcnt(0)" ::: "memory");
        __builtin_amdgcn_s_barrier();

        const unsigned short* sb = &smem[(kt & 1) * 8192];
        bf16x8 af[2], bfr[2], bfz[2], bfn[2];
        #pragma unroll
        for (int mi = 0; mi < 2; ++mi) {
            const int row = wm * 32 + mi * 16 + fr;
            af[mi] = *reinterpret_cast<const bf16x8*>(&sb[row * 32 + swz(kg, row)]);
        }
        #pragma unroll
        for (int ni = 0; ni < 2; ++ni) {
            const int row = wn * 32 + ni * 16 + fr;
            const int sw = swz(kg, row);
            bfr[ni] = *reinterpret_cast<const bf16x8*>(&sb[2048 + (row) * 32 + sw]);
            bfz[ni] = *reinterpret_cast<const bf16x8*>(&sb[2048 + (64 + row) * 32 + sw]);
            bfn[ni] = *reinterpret_cast<const bf16x8*>(&sb[2048 + (128 + row) * 32 + sw]);
        }
        asm volatile("s_waitcnt lgkmcnt(0)" ::: "memory");
        __builtin_amdgcn_s_barrier();
        // buffer now free for all waves: issue next stage BEFORE compute
        if (kt + 2 < nkt) stage(kt & 1, kt + 2);

        const bool p1 = (kt < nkt1);
        __builtin_amdgcn_s_setprio(1);
        #pragma unroll
        for (int mi = 0; mi < 2; ++mi)
            #pragma unroll
            for (int ni = 0; ni < 2; ++ni) {
                ar[mi][ni] = __builtin_amdgcn_mfma_f32_16x16x32_bf16(af[mi], bfr[ni], ar[mi][ni], 0, 0, 0);
                az[mi][ni] = __builtin_amdgcn_mfma_f32_16x16x32_bf16(af[mi], bfz[ni], az[mi][ni], 0, 0, 0);
                if (p1)
                    an[mi][ni] = __builtin_amdgcn_mfma_f32_16x16x32_bf16(af[mi], bfn[ni], an[mi][ni], 0, 0, 0);
                else
                    ah[mi][ni] = __builtin_amdgcn_mfma_f32_16x16x32_bf16(af[mi], bfn[ni], ah[mi][ni], 0, 0, 0);
            }
        __builtin_amdgcn_s_setprio(0);
    }

    #pragma unroll
    for (int ni = 0; ni < 2; ++ni) {
        const int j = j0 + wn * 32 + ni * 16 + fr;
        const float bir = b_ih[j],         bhr = b_hh[j];
        const float biz = b_ih[H + j],     bhz = b_hh[H + j];
        const float bin = b_ih[2 * H + j], bhn = b_hh[2 * H + j];
        #pragma unroll
        for (int mi = 0; mi < 2; ++mi) {
            #pragma unroll
            for (int r = 0; r < 4; ++r) {
                const int m = m0 + wm * 32 + mi * 16 + kg * 4 + r;
                const float rg = sigf(ar[mi][ni][r] + bir + bhr);
                const float zg = sigf(az[mi][ni][r] + biz + bhz);
                const float ng = tanhf_fast(an[mi][ni][r] + bin + rg * (ah[mi][ni][r] + bhn));
                const size_t off = (size_t)m * H + j;
                const float hv = bf2f(hbi[off]);
                hbo[off] = f2bf((1.f - zg) * ng + zg * hv);
            }
        }
    }
}

// ---------------------------------------------------------------------------
// m97-style GEMM, 3-deep pipeline, stage-early: C = A @ BT^T (+bias). 128x128.
// ---------------------------------------------------------------------------
__global__ __launch_bounds__(256)
void mfma_gemm128(const unsigned short* __restrict__ A,
                  const unsigned short* __restrict__ BT,
                  const float* __restrict__ bias,
                  float* __restrict__ C, int M, int N, int K)
{
    const int m0 = blockIdx.x * 128, n0 = blockIdx.y * 128;
    const int tid = (int)threadIdx.x, lane = tid & 63, wid = tid >> 6;
    const int wm = wid >> 1, wn = wid & 1;
    const int fr = lane & 15, kg = lane >> 4;
    const int lrow = lane >> 2;
    const int scol = swz(lane & 3, lrow);

    __shared__ unsigned short smem[3 * 8192];

    f32x4 acc[4][4];
    #pragma unroll
    for (int i = 0; i < 4; ++i)
        #pragma unroll
        for (int j = 0; j < 4; ++j)
            acc[i][j] = (f32x4){0.f, 0.f, 0.f, 0.f};

    auto stage = [&](int buf, int kt) {
        const int k0 = kt * 32;
        unsigned short* base = &smem[buf * 8192];
        #pragma unroll
        for (int q = 0; q < 4; ++q) {
            const int c = wid * 4 + q;
            const unsigned short* g = (c < 8)
                ? A + (size_t)(m0 + c * 16 + lrow) * K + k0 + scol
                : BT + (size_t)(n0 + (c - 8) * 16 + lrow) * K + k0 + scol;
            gload16(g, base + c * 512);
        }
    };

    const int nkt = K >> 5;
    stage(0, 0); stage(1, 1); stage(2, 2);
    int cur = 0;

    for (int kt = 0; kt < nkt; ++kt) {
        if (kt + 2 < nkt)      asm volatile("s_waitcnt vmcnt(8)" ::: "memory");
        else if (kt + 1 < nkt) asm volatile("s_waitcnt vmcnt(4)" ::: "memory");
        else                   asm volatile("s_waitcnt vmcnt(0)" ::: "memory");
        __builtin_amdgcn_s_barrier();

        const unsigned short* sb = &smem[cur * 8192];
        bf16x8 af[4], bf[4];
        #pragma unroll
        for (int mi = 0; mi < 4; ++mi) {
            const int row = wm * 64 + mi * 16 + fr;
            af[mi] = *reinterpret_cast<const bf16x8*>(&sb[row * 32 + swz(kg, row)]);
        }
        #pragma unroll
        for (int ni = 0; ni < 4; ++ni) {
            const int row = wn * 64 + ni * 16 + fr;
            bf[ni] = *reinterpret_cast<const bf16x8*>(&sb[4096 + row * 32 + swz(kg, row)]);
        }
        asm volatile("s_waitcnt lgkmcnt(0)" ::: "memory");
        __builtin_amdgcn_s_barrier();
        if (kt + 3 < nkt) stage(cur, kt + 3);

        __builtin_amdgcn_s_setprio(1);
        #pragma unroll
        for (int mi = 0; mi < 4; ++mi)
            #pragma unroll
            for (int ni = 0; ni < 4; ++ni)
                acc[mi][ni] = __builtin_amdgcn_mfma_f32_16x16x32_bf16(
                    af[mi], bf[ni], acc[mi][ni], 0, 0, 0);
        __builtin_amdgcn_s_setprio(0);
        cur = (cur == 2) ? 0 : cur + 1;
    }

    #pragma unroll
    for (int ni = 0; ni < 4; ++ni) {
        const int n = n0 + wn * 64 + ni * 16 + fr;
        const float bv = bias ? bias[n] : 0.f;
        #pragma unroll
        for (int mi = 0; mi < 4; ++mi)
            #pragma unroll
            for (int r = 0; r < 4; ++r) {
                const int m = m0 + wm * 64 + mi * 16 + kg * 4 + r;
                C[(size_t)m * N + n] = acc[mi][ni][r] + bv;
            }
    }
}

// ---------------------------------------------------------------------------
// Tree level mega-GEMM: G = h_c @ [U_iou | U_f]. 64x64 tile -> 512 blocks
// (2/CU). 3-deep pipeline, stage-early; 2 chunks/wave -> vmcnt(4)/2/0.
// Epilogue scatters to giou (atomic) / fcs (f=sig(G+xf[parent]), atomic).
// ---------------------------------------------------------------------------
__global__ __launch_bounds__(256, 4)
void tree_gemm(const unsigned short* __restrict__ hTb,
               const unsigned short* __restrict__ UcombT,  // [2048][512]
               const float* __restrict__ xg,               // [N][2048]
               const float* __restrict__ cT,               // [N][512]
               const int* __restrict__ parent,
               int cstart, int pstart,
               float* __restrict__ giou,                   // [PER][1536]
               float* __restrict__ fcs)                    // [PER][512]
{
    constexpr int H = 512, N4H = 2048, G3H = 1536;
    const int m0 = blockIdx.x * 64, n0 = blockIdx.y * 64;
    const int tid = (int)threadIdx.x, lane = tid & 63, wid = tid >> 6;
    const int wm = wid >> 1, wn = wid & 1;
    const int fr = lane & 15, kg = lane >> 4;
    const int lrow = lane >> 2;
    const int scol = swz(lane & 3, lrow);

    __shared__ unsigned short smem[3 * 4096];

    f32x4 acc[2][2];
    #pragma unroll
    for (int i = 0; i < 2; ++i)
        #pragma unroll
        for (int j = 0; j < 2; ++j)
            acc[i][j] = (f32x4){0.f, 0.f, 0.f, 0.f};

    auto stage = [&](int buf, int kt) {
        const int k0 = kt * 32;
        unsigned short* base = &smem[buf * 4096];
        #pragma unroll
        for (int q = 0; q < 2; ++q) {
            const int c = wid * 2 + q;   // 8 chunks
            const unsigned short* g = (c < 4)
                ? hTb + (size_t)(cstart + m0 + c * 16 + lrow) * H + k0 + scol
                : UcombT + (size_t)(n0 + (c - 4) * 16 + lrow) * H + k0 + scol;
            gload16(g, base + c * 512);
        }
    };

    constexpr int nkt = H / 32;  // 16
    stage(0, 0); stage(1, 1); stage(2, 2);
    int cur = 0;

    for (int kt = 0; kt < nkt; ++kt) {
        if (kt + 2 < nkt)      asm volatile("s_waitcnt vmcnt(4)" ::: "memory");
        else if (kt + 1 < nkt) asm volatile("s_waitcnt vmcnt(2)" ::: "memory");
        else                   asm volatile("s_waitcnt vmcnt(0)" ::: "memory");
        __builtin_amdgcn_s_barrier();

        const unsigned short* sb = &smem[cur * 4096];
        bf16x8 af[2], bf[2];
        #pragma unroll
        for (int mi = 0; mi < 2; ++mi) {
            const int row = wm * 32 + mi * 16 + fr;
            af[mi] = *reinterpret_cast<const bf16x8*>(&sb[row * 32 + swz(kg, row)]);
        }
        #pragma unroll
        for (int ni = 0; ni < 2; ++ni) {
            const int row = wn * 32 + ni * 16 + fr;
            bf[ni] = *reinterpret_cast<const bf16x8*>(&sb[2048 + row * 32 + swz(kg, row)]);
        }
        asm volatile("s_waitcnt lgkmcnt(0)" ::: "memory");
        __builtin_amdgcn_s_barrier();
        if (kt + 3 < nkt) stage(cur, kt + 3);

        __builtin_amdgcn_s_setprio(1);
        #pragma unroll
        for (int mi = 0; mi < 2; ++mi)
            #pragma unroll
            for (int ni = 0; ni < 2; ++ni)
                acc[mi][ni] = __builtin_amdgcn_mfma_f32_16x16x32_bf16(
                    af[mi], bf[ni], acc[mi][ni], 0, 0, 0);
        __builtin_amdgcn_s_setprio(0);
        cur = (cur == 2) ? 0 : cur + 1;
    }

    if (n0 < G3H) {
        #pragma unroll
        for (int mi = 0; mi < 2; ++mi)
            #pragma unroll
            for (int r = 0; r < 4; ++r) {
                const int m = m0 + wm * 32 + mi * 16 + kg * 4 + r;
                const int p = parent[cstart + m] - pstart;
                #pragma unroll
                for (int ni = 0; ni < 2; ++ni) {
                    const int n = n0 + wn * 32 + ni * 16 + fr;
                    atomicAdd(&giou[(size_t)p * G3H + n], acc[mi][ni][r]);
                }
            }
    } else {
        #pragma unroll
        for (int mi = 0; mi < 2; ++mi)
            #pragma unroll
            for (int r = 0; r < 4; ++r) {
                const int m = m0 + wm * 32 + mi * 16 + kg * 4 + r;
                const int child = cstart + m;
                const int p = parent[child];
                #pragma unroll
                for (int ni = 0; ni < 2; ++ni) {
                    const int jf = n0 + wn * 32 + ni * 16 + fr - G3H;
                    const float f = sigf(acc[mi][ni][r] + xg[(size_t)p * N4H + G3H + jf]);
                    atomicAdd(&fcs[(size_t)(p - pstart) * H + jf],
                              f * cT[(size_t)child * H + jf]);
                }
            }
    }
}

// ---------------------------------------------------------------------------
// level update; re-zeros exactly the giou/fcs slots it read (exclusive
// ownership) so no per-level memset is needed.
// ---------------------------------------------------------------------------
__global__ void level_update(const float* __restrict__ xg,
                             float* __restrict__ giou,
                             float* __restrict__ fcs,
                             float* __restrict__ cT, float* __restrict__ hT,
                             unsigned short* __restrict__ hb, int pstart)
{
    constexpr int H = 512, N4H = 2048, G3H = 1536;
    const int idx = blockIdx.x * blockDim.x + threadIdx.x;  // PER*H exact
    const int pi = idx >> 9, j = idx & (H - 1);
    const int p = pstart + pi;
    const size_t xb4 = (size_t)p * N4H;
    const size_t gb = (size_t)pi * G3H;
    const float ig = sigf(xg[xb4 + j] + giou[gb + j]);
    const float og = sigf(xg[xb4 + H + j] + giou[gb + H + j]);
    const float ug = tanhf_fast(xg[xb4 + 2 * H + j] + giou[gb + 2 * H + j]);
    const float cn = ig * ug + fcs[idx];
    const float hn = og * tanhf_fast(cn);
    const size_t off = (size_t)p * H + j;
    cT[off] = cn;
    hT[off] = hn;
    hb[off] = f2bf(hn);
    giou[gb + j] = 0.f;
    giou[gb + H + j] = 0.f;
    giou[gb + 2 * H + j] = 0.f;
    fcs[idx] = 0.f;
}

__global__ void gather_out_kernel(const float* __restrict__ c,
                                  const float* __restrict__ h,
                                  const int* __restrict__ root_ids,
                                  int nroot, float* __restrict__ out)
{
    constexpr int H = 512;
    const int idx = blockIdx.x * blockDim.x + threadIdx.x;  // nroot*H exact
    const int t = idx >> 9, j = idx & (H - 1);
    const int rid = root_ids[t];
    out[idx] = c[(size_t)rid * H + j];
    out[(size_t)nroot * H + idx] = h[(size_t)rid * H + j];
}

// ---------------------------------------------------------------------------
extern "C" void kernel_launch(void* const* d_in, const int* in_sizes, int n_in,
                              void* d_out, int out_size, void* d_ws, size_t ws_size,
                              hipStream_t stream)
{
    const float* x_seq = (const float*)d_in[0];
    const float* W_ih  = (const float*)d_in[1];
    const float* W_hh  = (const float*)d_in[2];
    const float* b_ih  = (const float*)d_in[3];
    const float* b_hh  = (const float*)d_in[4];
    const float* Wx    = (const float*)d_in[5];
    const float* bx    = (const float*)d_in[6];
    const float* U_iou = (const float*)d_in[7];
    const float* U_f   = (const float*)d_in[8];
    const int* parent  = (const int*)d_in[9];
    const int* root_ids = (const int*)d_in[11];

    const int threeH = in_sizes[3];          // 1536
    const int H   = threeH / 3;              // 512
    const int I   = in_sizes[1] / threeH;    // 256
    const int N   = in_sizes[9];             // 8192
    const int L   = in_sizes[0] / (N * I);   // 8
    const int PER = in_sizes[11];            // 1024
    const int D   = N / PER;                 // 8

    const size_t NH = (size_t)N * H;
    const size_t PH = (size_t)PER * H;

    // ---- workspace carve-up (xb aliases xg: xb dead before xg written) ----
    char* p = (char*)d_ws;
    const size_t zone_sz = ((size_t)N * 4 * H * 4 > (size_t)N * L * I * 2)
                         ? (size_t)N * 4 * H * 4 : (size_t)N * L * I * 2;
    unsigned short* xb = (unsigned short*)p;
    float* xg = (float*)p;                       p += zone_sz;
    unsigned short* hb0 = (unsigned short*)p;    p += NH * 2;
    unsigned short* hb1 = (unsigned short*)p;    p += NH * 2;
    float* cT = (float*)p;                       p += NH * 4;
    float* hT = (float*)p;                       p += NH * 4;
    unsigned short* WihT = (unsigned short*)p;   p += (size_t)threeH * I * 2;
    unsigned short* WhhT = (unsigned short*)p;   p += (size_t)threeH * H * 2;
    unsigned short* WxT  = (unsigned short*)p;   p += (size_t)4 * H * H * 2;
    unsigned short* UcombT = (unsigned short*)p; p += (size_t)4 * H * H * 2;
    float* giou = (float*)p;                     p += PH * 3 * 4;
    float* fcs  = (float*)p;                     p += PH * 4;   // adjacent to giou
    if ((size_t)(p - (char*)d_ws) > ws_size) return;

    // ---- prep ----
    {
        const int n = N * L * I;
        cvt_f32_bf16<<<(n / 4 + 255) / 256, 256, 0, stream>>>(x_seq, xb, n);
        dim3 blk(32, 8);
        transpose_cvt<<<dim3(threeH / 32, I / 32), blk, 0, stream>>>(W_ih, WihT, I, threeH);
        transpose_cvt<<<dim3(threeH / 32, H / 32), blk, 0, stream>>>(W_hh, WhhT, H, threeH);
        transpose_cvt<<<dim3(4 * H / 32, H / 32), blk, 0, stream>>>(Wx, WxT, H, 4 * H);
        transpose_cvt<<<dim3(threeH / 32, H / 32), blk, 0, stream>>>(U_iou, UcombT, H, threeH);
        transpose_cvt<<<dim3(H / 32, H / 32), blk, 0, stream>>>(
            U_f, UcombT + (size_t)threeH * H, H, H);
    }
    hipMemsetAsync(hb0, 0, NH * 2, stream);
    hipMemsetAsync(giou, 0, PH * 4 * 4, stream);   // giou + fcs once

    // ---- Phase 1: GRU (bf16 state ping-pong), 64x64 tiles, 1024 blocks ----
    {
        dim3 grid(N / 64, H / 64);
        for (int t = 0; t < L; ++t) {
            const unsigned short* hin = (t & 1) ? hb1 : hb0;
            unsigned short* hout = (t & 1) ? hb0 : hb1;
            gru_mfma<<<grid, 256, 0, stream>>>(xb, t, hin, hout,
                                               WihT, WhhT, b_ih, b_hh);
        }
        // L even -> enc bf16 in hb0
    }

    // ---- Phase 2: xg = enc @ Wx + bx ----
    mfma_gemm128<<<dim3(N / 128, 4 * H / 128), 256, 0, stream>>>(
        hb0, WxT, bx, xg, N, 4 * H, H);

    // ---- Phase 3: tree levels (deepest -> roots) ----
    unsigned short* hTb = hb1;  // tree h (bf16), free after GRU
    const int pw_blocks = (int)(PH / 256);

    for (int lvl = D - 1; lvl >= 0; --lvl) {
        const int pstart = lvl * PER;
        const int cstart = (lvl + 1) * PER;

        if (lvl < D - 1)
            tree_gemm<<<dim3(PER / 64, (4 * H) / 64), 256, 0, stream>>>(
                hTb, UcombT, xg, cT, parent, cstart, pstart, giou, fcs);

        level_update<<<pw_blocks, 256, 0, stream>>>(xg, giou, fcs, cT, hT,
                                                    hTb, pstart);
    }

    // ---- Phase 4: gather roots ----
    gather_out_kernel<<<pw_blocks, 256, 0, stream>>>(cT, hT, root_ids, PER,
                                                     (float*)d_out);
}